// Round 3
// baseline (2203.093 us; speedup 1.0000x reference)
//
#include <hip/hip_runtime.h>

// ---------- types / helpers ----------
typedef __bf16 bx8 __attribute__((ext_vector_type(8)));
typedef float fx4 __attribute__((ext_vector_type(4)));

#define GAS(p) ((const __attribute__((address_space(1))) void*)(const void*)(p))
#define LAS(p) ((__attribute__((address_space(3))) void*)(void*)(p))

__device__ __forceinline__ unsigned short f2bf(float f) {
  unsigned u = __builtin_bit_cast(unsigned, f);
  return (unsigned short)((u + 0x7fffu + ((u >> 16) & 1u)) >> 16);
}
__device__ __forceinline__ float bf2f(unsigned short s) {
  unsigned u = ((unsigned)s) << 16;
  return __builtin_bit_cast(float, u);
}

// ---------- weight transpose + bf16 cast: dst[l][n][k] = (bf16)src[l][k][n] ----------
__global__ __launch_bounds__(256) void wtrans_kernel(const float* __restrict__ src,
                                                     unsigned short* __restrict__ dst,
                                                     int K, int N, int total) {
  int i = blockIdx.x * 256 + threadIdx.x;
  if (i >= total) return;
  int nk = N * K;
  int l = i / nk;
  int r = i - l * nk;
  int n = r / K;
  int k = r - n * K;
  dst[i] = f2bf(src[(size_t)l * nk + (size_t)k * N + n]);
}

// ---------- embed: x + col_emb[t] + pos_emb[t+1] ----------
__global__ __launch_bounds__(256) void embed_kernel(const float4* __restrict__ x,
                                                    const float4* __restrict__ ce,
                                                    const float4* __restrict__ pe,
                                                    float4* __restrict__ o) {
  int i = blockIdx.x * 256 + threadIdx.x;  // over 128*256*64
  int c4 = i & 63;
  int t = (i >> 6) & 255;
  float4 a = x[i], b = ce[t * 64 + c4], p = pe[(t + 1) * 64 + c4];
  o[i] = make_float4(a.x + b.x + p.x, a.y + b.y + p.y, a.z + b.z + p.z, a.w + b.w + p.w);
}

// ---------- LayerNorm: one wave per row of 256. MODE 0: write bf16 normed; MODE 1: write (mean, rstd) ----------
template <int MODE>
__global__ __launch_bounds__(256) void ln_kernel(const float* __restrict__ x,
                                                 const float* __restrict__ gw,
                                                 const float* __restrict__ bw,
                                                 unsigned short* __restrict__ out,
                                                 float2* __restrict__ stats) {
  int row = blockIdx.x * 4 + (threadIdx.x >> 6);
  int lane = threadIdx.x & 63;
  const float4 v = *(const float4*)(x + (size_t)row * 256 + lane * 4);
  float s = v.x + v.y + v.z + v.w;
  float q = v.x * v.x + v.y * v.y + v.z * v.z + v.w * v.w;
#pragma unroll
  for (int off = 1; off < 64; off <<= 1) {
    s += __shfl_xor(s, off);
    q += __shfl_xor(q, off);
  }
  float mean = s * (1.0f / 256.0f);
  float rs = rsqrtf(q * (1.0f / 256.0f) - mean * mean + 1e-5f);
  if (MODE == 1) {
    if (lane == 0) stats[row] = make_float2(mean, rs);
    return;
  }
  float4 gv = *(const float4*)(gw + lane * 4);
  float4 bv = *(const float4*)(bw + lane * 4);
  ushort4 o;
  o.x = f2bf((v.x - mean) * rs * gv.x + bv.x);
  o.y = f2bf((v.y - mean) * rs * gv.y + bv.y);
  o.z = f2bf((v.z - mean) * rs * gv.z + bv.z);
  o.w = f2bf((v.w - mean) * rs * gv.w + bv.w);
  *(ushort4*)(out + (size_t)row * 256 + lane * 4) = o;
}

// ---------- swiglu: g = a * sigmoid(gate), gl = [a | gate], M_chunk rows ----------
__global__ __launch_bounds__(256) void swiglu_kernel(const unsigned short* __restrict__ gl,
                                                     unsigned short* __restrict__ g) {
  int i = blockIdx.x * 256 + threadIdx.x;  // over Mc*64 (4 elems each)
  int m = i >> 6;
  int c4 = (i & 63) * 4;
  const ushort4 a = *(const ushort4*)(gl + (size_t)m * 512 + c4);
  const ushort4 gt = *(const ushort4*)(gl + (size_t)m * 512 + 256 + c4);
  ushort4 o;
  o.x = f2bf(bf2f(a.x) / (1.0f + __expf(-bf2f(gt.x))));
  o.y = f2bf(bf2f(a.y) / (1.0f + __expf(-bf2f(gt.y))));
  o.z = f2bf(bf2f(a.z) / (1.0f + __expf(-bf2f(gt.z))));
  o.w = f2bf(bf2f(a.w) / (1.0f + __expf(-bf2f(gt.w))));
  *(ushort4*)(g + (size_t)m * 256 + c4) = o;
}

// ---------- final: out[b][c] = mean_t (x - m_t)*rs_t * fg[c] + fb[c]  (fp32 OUTPUT) ----------
__global__ __launch_bounds__(256) void mean_kernel(const float* __restrict__ x,
                                                   const float2* __restrict__ stats,
                                                   const float* __restrict__ fg,
                                                   const float* __restrict__ fb,
                                                   float* __restrict__ out) {
  int b = blockIdx.x, c = threadIdx.x;
  const float* xb = x + (size_t)b * 65536;
  const float2* st = stats + b * 256;
  float acc = 0.f;
  for (int t = 0; t < 256; ++t) {
    float2 s = st[t];
    acc += (xb[t * 256 + c] - s.x) * s.y;
  }
  out[b * 256 + c] = acc * (1.0f / 256.0f) * fg[c] + fb[c];
}

// ---------- GEMM: C[M x N] = A[M x K](bf16) * BT[N x K](bf16)^T, fused epilogues ----------
// EP 0: out_bf16 = acc + bvec
// EP 1: out_bf16 = gelu_exact(acc + bvec)
// EP 2: resid += acc + bvec + col_bias[t][n]   (write fp32 resid)
// EP 3: resid += acc + bvec                    (write fp32 resid)
template <int EP>
__global__ __launch_bounds__(256) void gemm_kernel(const unsigned short* __restrict__ A,
                                                   const unsigned short* __restrict__ BT,
                                                   const float* __restrict__ bvec,
                                                   const float* __restrict__ cbias,
                                                   float* __restrict__ resid,
                                                   unsigned short* __restrict__ outb,
                                                   int N, int K) {
  __shared__ unsigned short lA[128 * 32];
  __shared__ unsigned short lB[128 * 32];
  const int tid = threadIdx.x;
  const int lane = tid & 63, w = tid >> 6;
  const int wr = w >> 1, wc = w & 1;
  const int g = lane >> 4, lr = lane & 15;
  const int m0 = blockIdx.y * 128, n0 = blockIdx.x * 128;
  fx4 acc[4][4] = {};
  for (int kk = 0; kk < K; kk += 32) {
#pragma unroll
    for (int r = 0; r < 2; ++r) {
      int u = r * 256 + tid;
      int row = u >> 2, sl = u & 3;
      int c = sl ^ ((row >> 1) & 3);
      __builtin_amdgcn_global_load_lds(GAS(A + (size_t)(m0 + row) * K + kk + c * 8),
                                       LAS(&lA[u * 8]), 16, 0, 0);
      __builtin_amdgcn_global_load_lds(GAS(BT + (size_t)(n0 + row) * K + kk + c * 8),
                                       LAS(&lB[u * 8]), 16, 0, 0);
    }
    asm volatile("s_waitcnt vmcnt(0)" ::: "memory");
    __syncthreads();
    bx8 af[4], bq[4];
#pragma unroll
    for (int i = 0; i < 4; ++i) {
      int row = wr * 64 + i * 16 + lr;
      af[i] = *(const bx8*)&lA[row * 32 + (g ^ ((row >> 1) & 3)) * 8];
      int col = wc * 64 + i * 16 + lr;
      bq[i] = *(const bx8*)&lB[col * 32 + (g ^ ((col >> 1) & 3)) * 8];
    }
#pragma unroll
    for (int i = 0; i < 4; ++i)
#pragma unroll
      for (int j = 0; j < 4; ++j)
        acc[i][j] = __builtin_amdgcn_mfma_f32_16x16x32_bf16(af[i], bq[j], acc[i][j], 0, 0, 0);
    __syncthreads();
  }
#pragma unroll
  for (int i = 0; i < 4; ++i) {
#pragma unroll
    for (int j = 0; j < 4; ++j) {
      int ncol = n0 + wc * 64 + j * 16 + lr;
      float bv = bvec[ncol];
#pragma unroll
      for (int r = 0; r < 4; ++r) {
        int m = m0 + wr * 64 + i * 16 + g * 4 + r;
        float v = acc[i][j][r] + bv;
        if constexpr (EP == 1) v = 0.5f * v * (1.0f + erff(v * 0.70710678118654752f));
        if constexpr (EP == 0 || EP == 1) {
          outb[(size_t)m * N + ncol] = f2bf(v);
        } else {
          size_t idx = (size_t)m * N + ncol;
          if constexpr (EP == 2) v += cbias[(m & 255) * 256 + ncol];
          v += resid[idx];
          resid[idx] = v;
        }
      }
    }
  }
}

// ---------- fused attention v2: swapped QK^T, P fully in-register ----------
// One block per (b,h); 4 waves; each wave does 4 tiles of 16 q-rows.
// QK^T: sc = mfma(K,Q) -> lane (g,lr) holds s=16n+4g+r for its own t=t0+lr.
// Softmax: per-lane over 64 regs + shfl_xor(16,32) across g. P unnormalized (<=1).
// PV: O^T = mfma(V^T, P^T) with k-slot map sigma(g,j)=4g+(j&3)+16(j>>2) so the
// P^T B-fragment is exactly the lane's registers. 1/sum applied at store.
// LDS = 32 KB (Kl + Vl) -> 4 blocks/CU; no barriers in the main loop.
__global__ __launch_bounds__(256, 4) void attn_kernel(const unsigned short* __restrict__ qkv,
                                                      const float* __restrict__ cbias,
                                                      unsigned short* __restrict__ attnb) {
  __shared__ unsigned short Kl[256 * 32];  // [s][d], 16B-unit swizzled (GEMM-style)
  __shared__ unsigned short Vl[256 * 32];  // [c][g][d][j], unit-swizzled
  const int bh = blockIdx.x, b = bh >> 3, h = bh & 7;
  const int tid = threadIdx.x, lane = tid & 63, w = tid >> 6;
  const int g = lane >> 4, lr = lane & 15;
  const unsigned short* qb_ = qkv + (size_t)b * 196608;
  // stage K (linear global_load_lds dest, pre-swizzled source)
#pragma unroll
  for (int r = 0; r < 4; ++r) {
    int u = r * 256 + tid;
    int s = u >> 2, sl = u & 3;
    int c = sl ^ ((s >> 1) & 3);
    __builtin_amdgcn_global_load_lds(GAS(qb_ + (size_t)s * 768 + 256 + h * 32 + c * 8),
                                     LAS(&Kl[u * 8]), 16, 0, 0);
  }
  // stage V: thread owns source row s; Vl[((c*4+g)*32+d)*8 + j] = V[32c+4g+(j&3)+16(j>>2)][d]
  {
    const int s = tid;
    const unsigned short* vr = qb_ + (size_t)s * 768 + 512 + h * 32;
    const int c = s >> 5, s32 = s & 31;
    const int j = (s32 & 3) + ((s32 >> 4) << 2);
    const int gg = (s32 >> 2) & 3;
    union { ushort4 v4[8]; unsigned short e[32]; } vu;
#pragma unroll
    for (int i = 0; i < 8; ++i) vu.v4[i] = *(const ushort4*)(vr + i * 4);
#pragma unroll
    for (int d = 0; d < 32; ++d) {
      int u = c * 128 + gg * 32 + d;
      int up = (u & ~7) | ((u & 7) ^ ((u >> 3) & 7));
      Vl[up * 8 + j] = vu.e[d];
    }
  }
  asm volatile("s_waitcnt vmcnt(0)" ::: "memory");
  __syncthreads();
  const float scale = 0.17677669529663689f;
  const fx4 zero = {0.f, 0.f, 0.f, 0.f};
#pragma unroll 1
  for (int it = 0; it < 4; ++it) {
    const int t = it * 64 + w * 16 + lr;
    bx8 qf = *(const bx8*)(qb_ + (size_t)t * 768 + h * 32 + g * 8);
    float p[16][4];
    float mx = -1e30f;
#pragma unroll
    for (int n = 0; n < 16; ++n) {
      int sr = n * 16 + lr;
      bx8 kf = *(const bx8*)&Kl[sr * 32 + (g ^ ((sr >> 1) & 3)) * 8];
      fx4 sc = __builtin_amdgcn_mfma_f32_16x16x32_bf16(kf, qf, zero, 0, 0, 0);
      const float4 cb = *(const float4*)(cbias + (size_t)t * 256 + n * 16 + g * 4);
      p[n][0] = sc[0] * scale + cb.x;
      p[n][1] = sc[1] * scale + cb.y;
      p[n][2] = sc[2] * scale + cb.z;
      p[n][3] = sc[3] * scale + cb.w;
      mx = fmaxf(mx, fmaxf(fmaxf(p[n][0], p[n][1]), fmaxf(p[n][2], p[n][3])));
    }
    mx = fmaxf(mx, __shfl_xor(mx, 16));
    mx = fmaxf(mx, __shfl_xor(mx, 32));
    float sum = 0.f;
    bx8 bq[8];
#pragma unroll
    for (int c = 0; c < 8; ++c) {
      union { bx8 v; unsigned short u[8]; } pk;
#pragma unroll
      for (int jj = 0; jj < 8; ++jj) {
        float e = __expf(p[2 * c + (jj >> 2)][jj & 3] - mx);
        sum += e;
        pk.u[jj] = f2bf(e);
      }
      bq[c] = pk.v;
    }
    sum += __shfl_xor(sum, 16);
    sum += __shfl_xor(sum, 32);
    const float inv = 1.0f / sum;
    fx4 oa0 = zero, oa1 = zero;
#pragma unroll
    for (int c = 0; c < 8; ++c) {
      int u0 = c * 128 + g * 32 + lr;
      int u0p = (u0 & ~7) | ((u0 & 7) ^ ((u0 >> 3) & 7));
      bx8 vf0 = *(const bx8*)&Vl[u0p * 8];
      oa0 = __builtin_amdgcn_mfma_f32_16x16x32_bf16(vf0, bq[c], oa0, 0, 0, 0);
      int u1 = u0 + 16;
      int u1p = (u1 & ~7) | ((u1 & 7) ^ ((u1 >> 3) & 7));
      bx8 vf1 = *(const bx8*)&Vl[u1p * 8];
      oa1 = __builtin_amdgcn_mfma_f32_16x16x32_bf16(vf1, bq[c], oa1, 0, 0, 0);
    }
    ushort4 o0, o1;
    o0.x = f2bf(oa0[0] * inv); o0.y = f2bf(oa0[1] * inv);
    o0.z = f2bf(oa0[2] * inv); o0.w = f2bf(oa0[3] * inv);
    o1.x = f2bf(oa1[0] * inv); o1.y = f2bf(oa1[1] * inv);
    o1.z = f2bf(oa1[2] * inv); o1.w = f2bf(oa1[3] * inv);
    unsigned short* orow = attnb + (size_t)(b * 256 + t) * 256 + h * 32;
    *(ushort4*)(orow + 4 * g) = o0;
    *(ushort4*)(orow + 16 + 4 * g) = o1;
  }
}

// ---------- orchestration ----------
extern "C" void kernel_launch(void* const* d_in, const int* in_sizes, int n_in,
                              void* d_out, int out_size, void* d_ws, size_t ws_size,
                              hipStream_t stream) {
  (void)in_sizes; (void)n_in; (void)out_size; (void)ws_size;
  const float* x     = (const float*)d_in[0];
  const float* cemb  = (const float*)d_in[1];
  const float* pemb  = (const float*)d_in[2];
  const float* cbias = (const float*)d_in[3];
  const float* ln1g  = (const float*)d_in[4];
  const float* ln1b  = (const float*)d_in[5];
  const float* qkvw  = (const float*)d_in[6];
  const float* qkvb  = (const float*)d_in[7];
  const float* outw  = (const float*)d_in[8];
  const float* outbv = (const float*)d_in[9];
  const float* ln2g  = (const float*)d_in[10];
  const float* ln2b  = (const float*)d_in[11];
  const float* w1    = (const float*)d_in[12];
  const float* b1    = (const float*)d_in[13];
  const float* w2    = (const float*)d_in[14];
  const float* b2    = (const float*)d_in[15];
  const float* w3    = (const float*)d_in[16];
  const float* b3    = (const float*)d_in[17];
  const float* fing  = (const float*)d_in[18];
  const float* finb  = (const float*)d_in[19];

  char* ws = (char*)d_ws;
  // Workspace layout (125.0 MB total), bytes:
  //  R0 x_res fp32            [0,          33554432)
  //  R1 hn bf16 multiplex     [33554432,   50331648)   ln1-out -> attnb -> ln2-out -> g
  //  R2 big bf16              [50331648,  117440512)   qkv[M][768] -> (u_c[16384][1024] @+0 | gl_c[16384][512] @+32M)
  //  R3 wT bf16               [117440512, 130809856)
  //  R4 stats float2          [130809856, 131072000)
  float* x_res = (float*)(ws);
  unsigned short* hn   = (unsigned short*)(ws + 33554432);
  unsigned short* big  = (unsigned short*)(ws + 50331648);
  unsigned short* glc  = (unsigned short*)(ws + 83886080);
  unsigned short* wT   = (unsigned short*)(ws + 117440512);
  float2* stats = (float2*)(ws + 130809856);

  unsigned short* qkvwT = wT;                 // 6*768*256
  unsigned short* outwT = wT + 1179648;       // 6*256*256
  unsigned short* w1T   = wT + 1572864;       // 6*1024*256
  unsigned short* w2T   = wT + 3145728;       // 6*512*1024
  unsigned short* w3T   = wT + 6291456;       // 6*256*256

  wtrans_kernel<<<4608, 256, 0, stream>>>(qkvw, qkvwT, 256, 768, 1179648);
  wtrans_kernel<<<1536, 256, 0, stream>>>(outw, outwT, 256, 256, 393216);
  wtrans_kernel<<<6144, 256, 0, stream>>>(w1, w1T, 256, 1024, 1572864);
  wtrans_kernel<<<12288, 256, 0, stream>>>(w2, w2T, 1024, 512, 3145728);
  wtrans_kernel<<<1536, 256, 0, stream>>>(w3, w3T, 256, 256, 393216);
  embed_kernel<<<8192, 256, 0, stream>>>((const float4*)x, (const float4*)cemb,
                                         (const float4*)pemb, (float4*)x_res);
  for (int l = 0; l < 6; ++l) {
    ln_kernel<0><<<8192, 256, 0, stream>>>(x_res, ln1g + l * 256, ln1b + l * 256, hn, nullptr);
    gemm_kernel<0><<<dim3(6, 256), 256, 0, stream>>>(hn, qkvwT + (size_t)l * 196608,
                                                     qkvb + l * 768, nullptr, nullptr, big,
                                                     768, 256);
    attn_kernel<<<1024, 256, 0, stream>>>(big, cbias, hn);  // attnb -> R1 (ln1-out dead)
    gemm_kernel<2><<<dim3(2, 256), 256, 0, stream>>>(hn, outwT + (size_t)l * 65536,
                                                     outbv + l * 256, cbias, x_res, nullptr,
                                                     256, 256);
    ln_kernel<0><<<8192, 256, 0, stream>>>(x_res, ln2g + l * 256, ln2b + l * 256, hn, nullptr);
    // MLP in 2 row-chunks of 16384 (fits in R2 after qkv is consumed)
    for (int c = 0; c < 2; ++c) {
      const size_t ro = (size_t)c * 16384 * 256;
      gemm_kernel<1><<<dim3(8, 128), 256, 0, stream>>>(hn + ro, w1T + (size_t)l * 262144,
                                                       b1 + l * 1024, nullptr, nullptr, big,
                                                       1024, 256);
      gemm_kernel<0><<<dim3(4, 128), 256, 0, stream>>>(big, w2T + (size_t)l * 524288,
                                                       b2 + l * 512, nullptr, nullptr, glc,
                                                       512, 1024);
      swiglu_kernel<<<4096, 256, 0, stream>>>(glc, hn + ro);
      gemm_kernel<3><<<dim3(2, 128), 256, 0, stream>>>(hn + ro, w3T + (size_t)l * 65536,
                                                       b3 + l * 256, nullptr, x_res + ro,
                                                       nullptr, 256, 256);
    }
  }
  ln_kernel<1><<<8192, 256, 0, stream>>>(x_res, nullptr, nullptr, nullptr, stats);
  mean_kernel<<<128, 256, 0, stream>>>(x_res, stats, fing, finb, (float*)d_out);
}

// Round 4
// 1900.813 us; speedup vs baseline: 1.1590x; 1.1590x over previous
//
#include <hip/hip_runtime.h>

// ---------- types / helpers ----------
typedef __bf16 bx8 __attribute__((ext_vector_type(8)));
typedef float fx4 __attribute__((ext_vector_type(4)));

#define GAS(p) ((const __attribute__((address_space(1))) void*)(const void*)(p))
#define LAS(p) ((__attribute__((address_space(3))) void*)(void*)(p))

__device__ __forceinline__ unsigned short f2bf(float f) {
  unsigned u = __builtin_bit_cast(unsigned, f);
  return (unsigned short)((u + 0x7fffu + ((u >> 16) & 1u)) >> 16);
}
__device__ __forceinline__ float bf2f(unsigned short s) {
  unsigned u = ((unsigned)s) << 16;
  return __builtin_bit_cast(float, u);
}

// ---------- weight transpose + bf16 cast: dst[l][n][k] = (bf16)src[l][k][n] ----------
__global__ __launch_bounds__(256) void wtrans_kernel(const float* __restrict__ src,
                                                     unsigned short* __restrict__ dst,
                                                     int K, int N, int total) {
  int i = blockIdx.x * 256 + threadIdx.x;
  if (i >= total) return;
  int nk = N * K;
  int l = i / nk;
  int r = i - l * nk;
  int n = r / K;
  int k = r - n * K;
  dst[i] = f2bf(src[(size_t)l * nk + (size_t)k * N + n]);
}

// ---------- embed: x + col_emb[t] + pos_emb[t+1] ----------
__global__ __launch_bounds__(256) void embed_kernel(const float4* __restrict__ x,
                                                    const float4* __restrict__ ce,
                                                    const float4* __restrict__ pe,
                                                    float4* __restrict__ o) {
  int i = blockIdx.x * 256 + threadIdx.x;  // over 128*256*64
  int c4 = i & 63;
  int t = (i >> 6) & 255;
  float4 a = x[i], b = ce[t * 64 + c4], p = pe[(t + 1) * 64 + c4];
  o[i] = make_float4(a.x + b.x + p.x, a.y + b.y + p.y, a.z + b.z + p.z, a.w + b.w + p.w);
}

// ---------- LayerNorm: one wave per row of 256. MODE 0: write bf16 normed; MODE 1: write (mean, rstd) ----------
template <int MODE>
__global__ __launch_bounds__(256) void ln_kernel(const float* __restrict__ x,
                                                 const float* __restrict__ gw,
                                                 const float* __restrict__ bw,
                                                 unsigned short* __restrict__ out,
                                                 float2* __restrict__ stats) {
  int row = blockIdx.x * 4 + (threadIdx.x >> 6);
  int lane = threadIdx.x & 63;
  const float4 v = *(const float4*)(x + (size_t)row * 256 + lane * 4);
  float s = v.x + v.y + v.z + v.w;
  float q = v.x * v.x + v.y * v.y + v.z * v.z + v.w * v.w;
#pragma unroll
  for (int off = 1; off < 64; off <<= 1) {
    s += __shfl_xor(s, off);
    q += __shfl_xor(q, off);
  }
  float mean = s * (1.0f / 256.0f);
  float rs = rsqrtf(q * (1.0f / 256.0f) - mean * mean + 1e-5f);
  if (MODE == 1) {
    if (lane == 0) stats[row] = make_float2(mean, rs);
    return;
  }
  float4 gv = *(const float4*)(gw + lane * 4);
  float4 bv = *(const float4*)(bw + lane * 4);
  ushort4 o;
  o.x = f2bf((v.x - mean) * rs * gv.x + bv.x);
  o.y = f2bf((v.y - mean) * rs * gv.y + bv.y);
  o.z = f2bf((v.z - mean) * rs * gv.z + bv.z);
  o.w = f2bf((v.w - mean) * rs * gv.w + bv.w);
  *(ushort4*)(out + (size_t)row * 256 + lane * 4) = o;
}

// ---------- swiglu: g = a * sigmoid(gate), gl = [a | gate], M_chunk rows ----------
__global__ __launch_bounds__(256) void swiglu_kernel(const unsigned short* __restrict__ gl,
                                                     unsigned short* __restrict__ g) {
  int i = blockIdx.x * 256 + threadIdx.x;  // over Mc*64 (4 elems each)
  int m = i >> 6;
  int c4 = (i & 63) * 4;
  const ushort4 a = *(const ushort4*)(gl + (size_t)m * 512 + c4);
  const ushort4 gt = *(const ushort4*)(gl + (size_t)m * 512 + 256 + c4);
  ushort4 o;
  o.x = f2bf(bf2f(a.x) / (1.0f + __expf(-bf2f(gt.x))));
  o.y = f2bf(bf2f(a.y) / (1.0f + __expf(-bf2f(gt.y))));
  o.z = f2bf(bf2f(a.z) / (1.0f + __expf(-bf2f(gt.z))));
  o.w = f2bf(bf2f(a.w) / (1.0f + __expf(-bf2f(gt.w))));
  *(ushort4*)(g + (size_t)m * 256 + c4) = o;
}

// ---------- final: out[b][c] = mean_t (x - m_t)*rs_t * fg[c] + fb[c]  (fp32 OUTPUT) ----------
__global__ __launch_bounds__(256) void mean_kernel(const float* __restrict__ x,
                                                   const float2* __restrict__ stats,
                                                   const float* __restrict__ fg,
                                                   const float* __restrict__ fb,
                                                   float* __restrict__ out) {
  int b = blockIdx.x, c = threadIdx.x;
  const float* xb = x + (size_t)b * 65536;
  const float2* st = stats + b * 256;
  float acc = 0.f;
  for (int t = 0; t < 256; ++t) {
    float2 s = st[t];
    acc += (xb[t * 256 + c] - s.x) * s.y;
  }
  out[b * 256 + c] = acc * (1.0f / 256.0f) * fg[c] + fb[c];
}

// ---------- GEMM: C[M x N] = A[M x K](bf16) * BT[N x K](bf16)^T, fused epilogues ----------
// EP 0: out_bf16 = acc + bvec
// EP 1: out_bf16 = gelu_exact(acc + bvec)
// EP 2: resid += acc + bvec + col_bias[t][n]   (write fp32 resid)
// EP 3: resid += acc + bvec                    (write fp32 resid)
template <int EP>
__global__ __launch_bounds__(256) void gemm_kernel(const unsigned short* __restrict__ A,
                                                   const unsigned short* __restrict__ BT,
                                                   const float* __restrict__ bvec,
                                                   const float* __restrict__ cbias,
                                                   float* __restrict__ resid,
                                                   unsigned short* __restrict__ outb,
                                                   int N, int K) {
  __shared__ unsigned short lA[128 * 32];
  __shared__ unsigned short lB[128 * 32];
  const int tid = threadIdx.x;
  const int lane = tid & 63, w = tid >> 6;
  const int wr = w >> 1, wc = w & 1;
  const int g = lane >> 4, lr = lane & 15;
  const int m0 = blockIdx.y * 128, n0 = blockIdx.x * 128;
  fx4 acc[4][4] = {};
  for (int kk = 0; kk < K; kk += 32) {
#pragma unroll
    for (int r = 0; r < 2; ++r) {
      int u = r * 256 + tid;
      int row = u >> 2, sl = u & 3;
      int c = sl ^ ((row >> 1) & 3);
      __builtin_amdgcn_global_load_lds(GAS(A + (size_t)(m0 + row) * K + kk + c * 8),
                                       LAS(&lA[u * 8]), 16, 0, 0);
      __builtin_amdgcn_global_load_lds(GAS(BT + (size_t)(n0 + row) * K + kk + c * 8),
                                       LAS(&lB[u * 8]), 16, 0, 0);
    }
    asm volatile("s_waitcnt vmcnt(0)" ::: "memory");
    __syncthreads();
    bx8 af[4], bq[4];
#pragma unroll
    for (int i = 0; i < 4; ++i) {
      int row = wr * 64 + i * 16 + lr;
      af[i] = *(const bx8*)&lA[row * 32 + (g ^ ((row >> 1) & 3)) * 8];
      int col = wc * 64 + i * 16 + lr;
      bq[i] = *(const bx8*)&lB[col * 32 + (g ^ ((col >> 1) & 3)) * 8];
    }
#pragma unroll
    for (int i = 0; i < 4; ++i)
#pragma unroll
      for (int j = 0; j < 4; ++j)
        acc[i][j] = __builtin_amdgcn_mfma_f32_16x16x32_bf16(af[i], bq[j], acc[i][j], 0, 0, 0);
    __syncthreads();
  }
#pragma unroll
  for (int i = 0; i < 4; ++i) {
#pragma unroll
    for (int j = 0; j < 4; ++j) {
      int ncol = n0 + wc * 64 + j * 16 + lr;
      float bv = bvec[ncol];
#pragma unroll
      for (int r = 0; r < 4; ++r) {
        int m = m0 + wr * 64 + i * 16 + g * 4 + r;
        float v = acc[i][j][r] + bv;
        if constexpr (EP == 1) v = 0.5f * v * (1.0f + erff(v * 0.70710678118654752f));
        if constexpr (EP == 0 || EP == 1) {
          outb[(size_t)m * N + ncol] = f2bf(v);
        } else {
          size_t idx = (size_t)m * N + ncol;
          if constexpr (EP == 2) v += cbias[(m & 255) * 256 + ncol];
          v += resid[idx];
          resid[idx] = v;
        }
      }
    }
  }
}

// ---------- fused attention v2: swapped QK^T, P fully in-register ----------
// NOTE: NO min-waves launch-bounds arg — round-3 used (256,4), which capped the
// kernel at 64 VGPR and spilled p[16][4] to scratch (FETCH 229MB / WRITE 105MB
// of pure spill traffic). Plain (256) lets the allocator keep P in registers.
__global__ __launch_bounds__(256) void attn_kernel(const unsigned short* __restrict__ qkv,
                                                   const float* __restrict__ cbias,
                                                   unsigned short* __restrict__ attnb) {
  __shared__ unsigned short Kl[256 * 32];  // [s][d], 16B-unit swizzled (GEMM-style)
  __shared__ unsigned short Vl[256 * 32];  // [c][g][d][j], unit-swizzled
  const int bh = blockIdx.x, b = bh >> 3, h = bh & 7;
  const int tid = threadIdx.x, lane = tid & 63, w = tid >> 6;
  const int g = lane >> 4, lr = lane & 15;
  const unsigned short* qb_ = qkv + (size_t)b * 196608;
  // stage K (linear global_load_lds dest, pre-swizzled source)
#pragma unroll
  for (int r = 0; r < 4; ++r) {
    int u = r * 256 + tid;
    int s = u >> 2, sl = u & 3;
    int c = sl ^ ((s >> 1) & 3);
    __builtin_amdgcn_global_load_lds(GAS(qb_ + (size_t)s * 768 + 256 + h * 32 + c * 8),
                                     LAS(&Kl[u * 8]), 16, 0, 0);
  }
  // stage V: thread owns source row s; Vl[((c*4+g)*32+d)*8 + j] = V[32c+4g+(j&3)+16(j>>2)][d]
  {
    const int s = tid;
    const unsigned short* vr = qb_ + (size_t)s * 768 + 512 + h * 32;
    const int c = s >> 5, s32 = s & 31;
    const int j = (s32 & 3) + ((s32 >> 4) << 2);
    const int gg = (s32 >> 2) & 3;
    union { ushort4 v4[8]; unsigned short e[32]; } vu;
#pragma unroll
    for (int i = 0; i < 8; ++i) vu.v4[i] = *(const ushort4*)(vr + i * 4);
#pragma unroll
    for (int d = 0; d < 32; ++d) {
      int u = c * 128 + gg * 32 + d;
      int up = (u & ~7) | ((u & 7) ^ ((u >> 3) & 7));
      Vl[up * 8 + j] = vu.e[d];
    }
  }
  asm volatile("s_waitcnt vmcnt(0)" ::: "memory");
  __syncthreads();
  const float scale = 0.17677669529663689f;
  const fx4 zero = {0.f, 0.f, 0.f, 0.f};
#pragma unroll 1
  for (int it = 0; it < 4; ++it) {
    const int t = it * 64 + w * 16 + lr;
    bx8 qf = *(const bx8*)(qb_ + (size_t)t * 768 + h * 32 + g * 8);
    float p[16][4];
    float mx = -1e30f;
#pragma unroll
    for (int n = 0; n < 16; ++n) {
      int sr = n * 16 + lr;
      bx8 kf = *(const bx8*)&Kl[sr * 32 + (g ^ ((sr >> 1) & 3)) * 8];
      fx4 sc = __builtin_amdgcn_mfma_f32_16x16x32_bf16(kf, qf, zero, 0, 0, 0);
      const float4 cb = *(const float4*)(cbias + (size_t)t * 256 + n * 16 + g * 4);
      p[n][0] = sc[0] * scale + cb.x;
      p[n][1] = sc[1] * scale + cb.y;
      p[n][2] = sc[2] * scale + cb.z;
      p[n][3] = sc[3] * scale + cb.w;
      mx = fmaxf(mx, fmaxf(fmaxf(p[n][0], p[n][1]), fmaxf(p[n][2], p[n][3])));
    }
    mx = fmaxf(mx, __shfl_xor(mx, 16));
    mx = fmaxf(mx, __shfl_xor(mx, 32));
    float sum = 0.f;
    bx8 bq[8];
#pragma unroll
    for (int c = 0; c < 8; ++c) {
      union { bx8 v; unsigned short u[8]; } pk;
#pragma unroll
      for (int jj = 0; jj < 8; ++jj) {
        float e = __expf(p[2 * c + (jj >> 2)][jj & 3] - mx);
        sum += e;
        pk.u[jj] = f2bf(e);
      }
      bq[c] = pk.v;
    }
    sum += __shfl_xor(sum, 16);
    sum += __shfl_xor(sum, 32);
    const float inv = 1.0f / sum;
    fx4 oa0 = zero, oa1 = zero;
#pragma unroll
    for (int c = 0; c < 8; ++c) {
      int u0 = c * 128 + g * 32 + lr;
      int u0p = (u0 & ~7) | ((u0 & 7) ^ ((u0 >> 3) & 7));
      bx8 vf0 = *(const bx8*)&Vl[u0p * 8];
      oa0 = __builtin_amdgcn_mfma_f32_16x16x32_bf16(vf0, bq[c], oa0, 0, 0, 0);
      int u1 = u0 + 16;
      int u1p = (u1 & ~7) | ((u1 & 7) ^ ((u1 >> 3) & 7));
      bx8 vf1 = *(const bx8*)&Vl[u1p * 8];
      oa1 = __builtin_amdgcn_mfma_f32_16x16x32_bf16(vf1, bq[c], oa1, 0, 0, 0);
    }
    ushort4 o0, o1;
    o0.x = f2bf(oa0[0] * inv); o0.y = f2bf(oa0[1] * inv);
    o0.z = f2bf(oa0[2] * inv); o0.w = f2bf(oa0[3] * inv);
    o1.x = f2bf(oa1[0] * inv); o1.y = f2bf(oa1[1] * inv);
    o1.z = f2bf(oa1[2] * inv); o1.w = f2bf(oa1[3] * inv);
    unsigned short* orow = attnb + (size_t)(b * 256 + t) * 256 + h * 32;
    *(ushort4*)(orow + 4 * g) = o0;
    *(ushort4*)(orow + 16 + 4 * g) = o1;
  }
}

// ---------- orchestration ----------
extern "C" void kernel_launch(void* const* d_in, const int* in_sizes, int n_in,
                              void* d_out, int out_size, void* d_ws, size_t ws_size,
                              hipStream_t stream) {
  (void)in_sizes; (void)n_in; (void)out_size; (void)ws_size;
  const float* x     = (const float*)d_in[0];
  const float* cemb  = (const float*)d_in[1];
  const float* pemb  = (const float*)d_in[2];
  const float* cbias = (const float*)d_in[3];
  const float* ln1g  = (const float*)d_in[4];
  const float* ln1b  = (const float*)d_in[5];
  const float* qkvw  = (const float*)d_in[6];
  const float* qkvb  = (const float*)d_in[7];
  const float* outw  = (const float*)d_in[8];
  const float* outbv = (const float*)d_in[9];
  const float* ln2g  = (const float*)d_in[10];
  const float* ln2b  = (const float*)d_in[11];
  const float* w1    = (const float*)d_in[12];
  const float* b1    = (const float*)d_in[13];
  const float* w2    = (const float*)d_in[14];
  const float* b2    = (const float*)d_in[15];
  const float* w3    = (const float*)d_in[16];
  const float* b3    = (const float*)d_in[17];
  const float* fing  = (const float*)d_in[18];
  const float* finb  = (const float*)d_in[19];

  char* ws = (char*)d_ws;
  // Workspace layout (125.0 MB total), bytes:
  //  R0 x_res fp32            [0,          33554432)
  //  R1 hn bf16 multiplex     [33554432,   50331648)   ln1-out -> attnb -> ln2-out -> g
  //  R2 big bf16              [50331648,  117440512)   qkv[M][768] -> (u_c[16384][1024] @+0 | gl_c[16384][512] @+32M)
  //  R3 wT bf16               [117440512, 130809856)
  //  R4 stats float2          [130809856, 131072000)
  float* x_res = (float*)(ws);
  unsigned short* hn   = (unsigned short*)(ws + 33554432);
  unsigned short* big  = (unsigned short*)(ws + 50331648);
  unsigned short* glc  = (unsigned short*)(ws + 83886080);
  unsigned short* wT   = (unsigned short*)(ws + 117440512);
  float2* stats = (float2*)(ws + 130809856);

  unsigned short* qkvwT = wT;                 // 6*768*256
  unsigned short* outwT = wT + 1179648;       // 6*256*256
  unsigned short* w1T   = wT + 1572864;       // 6*1024*256
  unsigned short* w2T   = wT + 3145728;       // 6*512*1024
  unsigned short* w3T   = wT + 6291456;       // 6*256*256

  wtrans_kernel<<<4608, 256, 0, stream>>>(qkvw, qkvwT, 256, 768, 1179648);
  wtrans_kernel<<<1536, 256, 0, stream>>>(outw, outwT, 256, 256, 393216);
  wtrans_kernel<<<6144, 256, 0, stream>>>(w1, w1T, 256, 1024, 1572864);
  wtrans_kernel<<<12288, 256, 0, stream>>>(w2, w2T, 1024, 512, 3145728);
  wtrans_kernel<<<1536, 256, 0, stream>>>(w3, w3T, 256, 256, 393216);
  embed_kernel<<<8192, 256, 0, stream>>>((const float4*)x, (const float4*)cemb,
                                         (const float4*)pemb, (float4*)x_res);
  for (int l = 0; l < 6; ++l) {
    ln_kernel<0><<<8192, 256, 0, stream>>>(x_res, ln1g + l * 256, ln1b + l * 256, hn, nullptr);
    gemm_kernel<0><<<dim3(6, 256), 256, 0, stream>>>(hn, qkvwT + (size_t)l * 196608,
                                                     qkvb + l * 768, nullptr, nullptr, big,
                                                     768, 256);
    attn_kernel<<<1024, 256, 0, stream>>>(big, cbias, hn);  // attnb -> R1 (ln1-out dead)
    gemm_kernel<2><<<dim3(2, 256), 256, 0, stream>>>(hn, outwT + (size_t)l * 65536,
                                                     outbv + l * 256, cbias, x_res, nullptr,
                                                     256, 256);
    ln_kernel<0><<<8192, 256, 0, stream>>>(x_res, ln2g + l * 256, ln2b + l * 256, hn, nullptr);
    // MLP in 2 row-chunks of 16384 (fits in R2 after qkv is consumed)
    for (int c = 0; c < 2; ++c) {
      const size_t ro = (size_t)c * 16384 * 256;
      gemm_kernel<1><<<dim3(8, 128), 256, 0, stream>>>(hn + ro, w1T + (size_t)l * 262144,
                                                       b1 + l * 1024, nullptr, nullptr, big,
                                                       1024, 256);
      gemm_kernel<0><<<dim3(4, 128), 256, 0, stream>>>(big, w2T + (size_t)l * 524288,
                                                       b2 + l * 512, nullptr, nullptr, glc,
                                                       512, 1024);
      swiglu_kernel<<<4096, 256, 0, stream>>>(glc, hn + ro);
      gemm_kernel<3><<<dim3(2, 128), 256, 0, stream>>>(hn + ro, w3T + (size_t)l * 65536,
                                                       b3 + l * 256, nullptr, x_res + ro,
                                                       nullptr, 256, 256);
    }
  }
  ln_kernel<1><<<8192, 256, 0, stream>>>(x_res, nullptr, nullptr, nullptr, stats);
  mean_kernel<<<128, 256, 0, stream>>>(x_res, stats, fing, finb, (float*)d_out);
}

// Round 5
// 1823.641 us; speedup vs baseline: 1.2081x; 1.0423x over previous
//
#include <hip/hip_runtime.h>

// ---------- types / helpers ----------
typedef __bf16 bx8 __attribute__((ext_vector_type(8)));
typedef float fx4 __attribute__((ext_vector_type(4)));

#define GAS(p) ((const __attribute__((address_space(1))) void*)(const void*)(p))
#define LAS(p) ((__attribute__((address_space(3))) void*)(void*)(p))

__device__ __forceinline__ unsigned short f2bf(float f) {
  return __builtin_bit_cast(unsigned short, (__bf16)f);  // native RTNE, pairs to v_cvt_pk_bf16_f32
}
__device__ __forceinline__ float bf2f(unsigned short s) {
  unsigned u = ((unsigned)s) << 16;
  return __builtin_bit_cast(float, u);
}

// ---------- tiled weight transpose + bf16 cast: dst[l][n][k] = (bf16)src[l][k][n] ----------
// grid (N/64, K/64, L), block 256. Coalesced read AND write via LDS 64x64 tile.
__global__ __launch_bounds__(256) void wtrans_kernel(const float* __restrict__ src,
                                                     unsigned short* __restrict__ dst,
                                                     int K, int N) {
  __shared__ unsigned short t[64][68];  // stride 68 ush = 34 dw -> 2-way bank alias (free)
  const int l = blockIdx.z;
  const float* s = src + (size_t)l * K * N;
  unsigned short* d = dst + (size_t)l * N * K;
  const int n0 = blockIdx.x * 64, k0 = blockIdx.y * 64;
  const int tx = threadIdx.x & 63, ty = threadIdx.x >> 6;
#pragma unroll
  for (int r = 0; r < 64; r += 4)
    t[tx][ty + r] = f2bf(s[(size_t)(k0 + ty + r) * N + n0 + tx]);
  __syncthreads();
#pragma unroll
  for (int r = 0; r < 64; r += 4)
    d[(size_t)(n0 + ty + r) * K + k0 + tx] = t[ty + r][tx];
}

// ---------- embed: x + col_emb[t] + pos_emb[t+1] ----------
__global__ __launch_bounds__(256) void embed_kernel(const float4* __restrict__ x,
                                                    const float4* __restrict__ ce,
                                                    const float4* __restrict__ pe,
                                                    float4* __restrict__ o) {
  int i = blockIdx.x * 256 + threadIdx.x;  // over 128*256*64
  int c4 = i & 63;
  int t = (i >> 6) & 255;
  float4 a = x[i], b = ce[t * 64 + c4], p = pe[(t + 1) * 64 + c4];
  o[i] = make_float4(a.x + b.x + p.x, a.y + b.y + p.y, a.z + b.z + p.z, a.w + b.w + p.w);
}

// ---------- LayerNorm: one wave per row of 256. MODE 0: write bf16 normed; MODE 1: write (mean, rstd) ----------
template <int MODE>
__global__ __launch_bounds__(256) void ln_kernel(const float* __restrict__ x,
                                                 const float* __restrict__ gw,
                                                 const float* __restrict__ bw,
                                                 unsigned short* __restrict__ out,
                                                 float2* __restrict__ stats) {
  int row = blockIdx.x * 4 + (threadIdx.x >> 6);
  int lane = threadIdx.x & 63;
  const float4 v = *(const float4*)(x + (size_t)row * 256 + lane * 4);
  float s = v.x + v.y + v.z + v.w;
  float q = v.x * v.x + v.y * v.y + v.z * v.z + v.w * v.w;
#pragma unroll
  for (int off = 1; off < 64; off <<= 1) {
    s += __shfl_xor(s, off);
    q += __shfl_xor(q, off);
  }
  float mean = s * (1.0f / 256.0f);
  float rs = rsqrtf(q * (1.0f / 256.0f) - mean * mean + 1e-5f);
  if (MODE == 1) {
    if (lane == 0) stats[row] = make_float2(mean, rs);
    return;
  }
  float4 gv = *(const float4*)(gw + lane * 4);
  float4 bv = *(const float4*)(bw + lane * 4);
  ushort4 o;
  o.x = f2bf((v.x - mean) * rs * gv.x + bv.x);
  o.y = f2bf((v.y - mean) * rs * gv.y + bv.y);
  o.z = f2bf((v.z - mean) * rs * gv.z + bv.z);
  o.w = f2bf((v.w - mean) * rs * gv.w + bv.w);
  *(ushort4*)(out + (size_t)row * 256 + lane * 4) = o;
}

// ---------- swiglu: g = a * sigmoid(gate), gl = [a | gate], M_chunk rows ----------
__global__ __launch_bounds__(256) void swiglu_kernel(const unsigned short* __restrict__ gl,
                                                     unsigned short* __restrict__ g) {
  int i = blockIdx.x * 256 + threadIdx.x;  // over Mc*64 (4 elems each)
  int m = i >> 6;
  int c4 = (i & 63) * 4;
  const ushort4 a = *(const ushort4*)(gl + (size_t)m * 512 + c4);
  const ushort4 gt = *(const ushort4*)(gl + (size_t)m * 512 + 256 + c4);
  ushort4 o;
  o.x = f2bf(bf2f(a.x) / (1.0f + __expf(-bf2f(gt.x))));
  o.y = f2bf(bf2f(a.y) / (1.0f + __expf(-bf2f(gt.y))));
  o.z = f2bf(bf2f(a.z) / (1.0f + __expf(-bf2f(gt.z))));
  o.w = f2bf(bf2f(a.w) / (1.0f + __expf(-bf2f(gt.w))));
  *(ushort4*)(g + (size_t)m * 256 + c4) = o;
}

// ---------- final mean, two-stage ----------
__global__ __launch_bounds__(256) void mean_part_kernel(const float* __restrict__ x,
                                                        const float2* __restrict__ stats,
                                                        float* __restrict__ part) {
  int b = blockIdx.x, half = blockIdx.y, c = threadIdx.x;
  const float* xb = x + (size_t)b * 65536 + half * 32768;
  const float2* st = stats + b * 256 + half * 128;
  float acc = 0.f;
#pragma unroll 4
  for (int t = 0; t < 128; ++t) {
    float2 s = st[t];
    acc += (xb[t * 256 + c] - s.x) * s.y;
  }
  part[(size_t)(b * 2 + half) * 256 + c] = acc;
}
__global__ __launch_bounds__(256) void mean_fin_kernel(const float* __restrict__ part,
                                                       const float* __restrict__ fg,
                                                       const float* __restrict__ fb,
                                                       float* __restrict__ out) {
  int b = blockIdx.x, c = threadIdx.x;
  out[b * 256 + c] =
      (part[(size_t)(2 * b) * 256 + c] + part[(size_t)(2 * b + 1) * 256 + c]) *
          (1.0f / 256.0f) * fg[c] + fb[c];
}

// ---------- GEMM: C[M x N] = A[M x K](bf16) * BT[N x K](bf16)^T, fused epilogues ----------
// EP 0: out_bf16 = acc + bvec
// EP 1: out_bf16 = gelu_exact(acc + bvec)
// EP 2: resid += acc + bvec + col_bias[t][n]   (write fp32 resid)
// EP 3: resid += acc + bvec                    (write fp32 resid)
// 128x128 tile, BK=32, 4 waves (2x2). 2-PHASE pipeline: double-buffered LDS,
// next tile's global_load_lds issued BEFORE current tile's compute; ONE barrier
// per K-step (its vmcnt(0) drain covers the prefetch). T3-minimum recipe.
template <int EP>
__global__ __launch_bounds__(256) void gemm_kernel(const unsigned short* __restrict__ A,
                                                   const unsigned short* __restrict__ BT,
                                                   const float* __restrict__ bvec,
                                                   const float* __restrict__ cbias,
                                                   float* __restrict__ resid,
                                                   unsigned short* __restrict__ outb,
                                                   int N, int K) {
  __shared__ unsigned short lA[2][128 * 32];
  __shared__ unsigned short lB[2][128 * 32];
  const int tid = threadIdx.x;
  const int lane = tid & 63, w = tid >> 6;
  const int wr = w >> 1, wc = w & 1;
  const int g = lane >> 4, lr = lane & 15;
  const int m0 = blockIdx.y * 128, n0 = blockIdx.x * 128;
  fx4 acc[4][4] = {};

  auto STAGE = [&](int buf, int kk) {
#pragma unroll
    for (int r = 0; r < 2; ++r) {
      int u = r * 256 + tid;
      int row = u >> 2, sl = u & 3;
      int c = sl ^ ((row >> 1) & 3);
      __builtin_amdgcn_global_load_lds(GAS(A + (size_t)(m0 + row) * K + kk + c * 8),
                                       LAS(&lA[buf][u * 8]), 16, 0, 0);
      __builtin_amdgcn_global_load_lds(GAS(BT + (size_t)(n0 + row) * K + kk + c * 8),
                                       LAS(&lB[buf][u * 8]), 16, 0, 0);
    }
  };
  auto COMPUTE = [&](int buf) {
    bx8 af[4], bq[4];
#pragma unroll
    for (int i = 0; i < 4; ++i) {
      int row = wr * 64 + i * 16 + lr;
      af[i] = *(const bx8*)&lA[buf][row * 32 + (g ^ ((row >> 1) & 3)) * 8];
      int col = wc * 64 + i * 16 + lr;
      bq[i] = *(const bx8*)&lB[buf][col * 32 + (g ^ ((col >> 1) & 3)) * 8];
    }
#pragma unroll
    for (int i = 0; i < 4; ++i)
#pragma unroll
      for (int j = 0; j < 4; ++j)
        acc[i][j] = __builtin_amdgcn_mfma_f32_16x16x32_bf16(af[i], bq[j], acc[i][j], 0, 0, 0);
  };

  STAGE(0, 0);
  asm volatile("s_waitcnt vmcnt(0)" ::: "memory");
  __syncthreads();
  int cur = 0;
  const int nt = K >> 5;
  for (int t2 = 1; t2 < nt; ++t2) {
    STAGE(cur ^ 1, t2 * 32);      // prefetch next tile (in flight during compute)
    COMPUTE(cur);
    __syncthreads();              // drains vmcnt(0) (prefetch done) + readers done
    cur ^= 1;
  }
  COMPUTE(cur);

  // epilogue. C/D layout: col = lane&15, row = 4*(lane>>4) + reg  (HW-verified)
#pragma unroll
  for (int i = 0; i < 4; ++i) {
#pragma unroll
    for (int j = 0; j < 4; ++j) {
      int ncol = n0 + wc * 64 + j * 16 + lr;
      float bv = bvec[ncol];
#pragma unroll
      for (int r = 0; r < 4; ++r) {
        int m = m0 + wr * 64 + i * 16 + g * 4 + r;
        float v = acc[i][j][r] + bv;
        if constexpr (EP == 1) v = 0.5f * v * (1.0f + erff(v * 0.70710678118654752f));
        if constexpr (EP == 0 || EP == 1) {
          outb[(size_t)m * N + ncol] = f2bf(v);
        } else {
          size_t idx = (size_t)m * N + ncol;
          if constexpr (EP == 2) v += cbias[(m & 255) * 256 + ncol];
          v += resid[idx];
          resid[idx] = v;
        }
      }
    }
  }
}

// ---------- fused attention v2: swapped QK^T, P fully in-register ----------
// NOTE: NO min-waves launch-bounds arg — (256,4) capped VGPR at 64 and spilled
// p[16][4] to scratch (round-3: 229MB FETCH of spill traffic). Plain (256).
__global__ __launch_bounds__(256) void attn_kernel(const unsigned short* __restrict__ qkv,
                                                   const float* __restrict__ cbias,
                                                   unsigned short* __restrict__ attnb) {
  __shared__ unsigned short Kl[256 * 32];  // [s][d], 16B-unit swizzled (GEMM-style)
  __shared__ unsigned short Vl[256 * 32];  // [c][g][d][j], unit-swizzled
  const int bh = blockIdx.x, b = bh >> 3, h = bh & 7;
  const int tid = threadIdx.x, lane = tid & 63, w = tid >> 6;
  const int g = lane >> 4, lr = lane & 15;
  const unsigned short* qb_ = qkv + (size_t)b * 196608;
#pragma unroll
  for (int r = 0; r < 4; ++r) {
    int u = r * 256 + tid;
    int s = u >> 2, sl = u & 3;
    int c = sl ^ ((s >> 1) & 3);
    __builtin_amdgcn_global_load_lds(GAS(qb_ + (size_t)s * 768 + 256 + h * 32 + c * 8),
                                     LAS(&Kl[u * 8]), 16, 0, 0);
  }
  // stage V: thread owns source row s; Vl[((c*4+g)*32+d)*8 + j] = V[32c+4g+(j&3)+16(j>>2)][d]
  {
    const int s = tid;
    const unsigned short* vr = qb_ + (size_t)s * 768 + 512 + h * 32;
    const int c = s >> 5, s32 = s & 31;
    const int j = (s32 & 3) + ((s32 >> 4) << 2);
    const int gg = (s32 >> 2) & 3;
    union { ushort4 v4[8]; unsigned short e[32]; } vu;
#pragma unroll
    for (int i = 0; i < 8; ++i) vu.v4[i] = *(const ushort4*)(vr + i * 4);
#pragma unroll
    for (int d = 0; d < 32; ++d) {
      int u = c * 128 + gg * 32 + d;
      int up = (u & ~7) | ((u & 7) ^ ((u >> 3) & 7));
      Vl[up * 8 + j] = vu.e[d];
    }
  }
  asm volatile("s_waitcnt vmcnt(0)" ::: "memory");
  __syncthreads();
  const float scale = 0.17677669529663689f;
  const fx4 zero = {0.f, 0.f, 0.f, 0.f};
#pragma unroll 1
  for (int it = 0; it < 4; ++it) {
    const int t = it * 64 + w * 16 + lr;
    bx8 qf = *(const bx8*)(qb_ + (size_t)t * 768 + h * 32 + g * 8);
    float p[16][4];
    float mx = -1e30f;
#pragma unroll
    for (int n = 0; n < 16; ++n) {
      int sr = n * 16 + lr;
      bx8 kf = *(const bx8*)&Kl[sr * 32 + (g ^ ((sr >> 1) & 3)) * 8];
      fx4 sc = __builtin_amdgcn_mfma_f32_16x16x32_bf16(kf, qf, zero, 0, 0, 0);
      const float4 cb = *(const float4*)(cbias + (size_t)t * 256 + n * 16 + g * 4);
      p[n][0] = sc[0] * scale + cb.x;
      p[n][1] = sc[1] * scale + cb.y;
      p[n][2] = sc[2] * scale + cb.z;
      p[n][3] = sc[3] * scale + cb.w;
      mx = fmaxf(mx, fmaxf(fmaxf(p[n][0], p[n][1]), fmaxf(p[n][2], p[n][3])));
    }
    mx = fmaxf(mx, __shfl_xor(mx, 16));
    mx = fmaxf(mx, __shfl_xor(mx, 32));
    float sum = 0.f;
    bx8 bq[8];
#pragma unroll
    for (int c = 0; c < 8; ++c) {
      union { bx8 v; unsigned short u[8]; } pk;
#pragma unroll
      for (int jj = 0; jj < 8; ++jj) {
        float e = __expf(p[2 * c + (jj >> 2)][jj & 3] - mx);
        sum += e;
        pk.u[jj] = f2bf(e);
      }
      bq[c] = pk.v;
    }
    sum += __shfl_xor(sum, 16);
    sum += __shfl_xor(sum, 32);
    const float inv = 1.0f / sum;
    fx4 oa0 = zero, oa1 = zero;
#pragma unroll
    for (int c = 0; c < 8; ++c) {
      int u0 = c * 128 + g * 32 + lr;
      int u0p = (u0 & ~7) | ((u0 & 7) ^ ((u0 >> 3) & 7));
      bx8 vf0 = *(const bx8*)&Vl[u0p * 8];
      oa0 = __builtin_amdgcn_mfma_f32_16x16x32_bf16(vf0, bq[c], oa0, 0, 0, 0);
      int u1 = u0 + 16;
      int u1p = (u1 & ~7) | ((u1 & 7) ^ ((u1 >> 3) & 7));
      bx8 vf1 = *(const bx8*)&Vl[u1p * 8];
      oa1 = __builtin_amdgcn_mfma_f32_16x16x32_bf16(vf1, bq[c], oa1, 0, 0, 0);
    }
    ushort4 o0, o1;
    o0.x = f2bf(oa0[0] * inv); o0.y = f2bf(oa0[1] * inv);
    o0.z = f2bf(oa0[2] * inv); o0.w = f2bf(oa0[3] * inv);
    o1.x = f2bf(oa1[0] * inv); o1.y = f2bf(oa1[1] * inv);
    o1.z = f2bf(oa1[2] * inv); o1.w = f2bf(oa1[3] * inv);
    unsigned short* orow = attnb + (size_t)(b * 256 + t) * 256 + h * 32;
    *(ushort4*)(orow + 4 * g) = o0;
    *(ushort4*)(orow + 16 + 4 * g) = o1;
  }
}

// ---------- orchestration ----------
extern "C" void kernel_launch(void* const* d_in, const int* in_sizes, int n_in,
                              void* d_out, int out_size, void* d_ws, size_t ws_size,
                              hipStream_t stream) {
  (void)in_sizes; (void)n_in; (void)out_size; (void)ws_size;
  const float* x     = (const float*)d_in[0];
  const float* cemb  = (const float*)d_in[1];
  const float* pemb  = (const float*)d_in[2];
  const float* cbias = (const float*)d_in[3];
  const float* ln1g  = (const float*)d_in[4];
  const float* ln1b  = (const float*)d_in[5];
  const float* qkvw  = (const float*)d_in[6];
  const float* qkvb  = (const float*)d_in[7];
  const float* outw  = (const float*)d_in[8];
  const float* outbv = (const float*)d_in[9];
  const float* ln2g  = (const float*)d_in[10];
  const float* ln2b  = (const float*)d_in[11];
  const float* w1    = (const float*)d_in[12];
  const float* b1    = (const float*)d_in[13];
  const float* w2    = (const float*)d_in[14];
  const float* b2    = (const float*)d_in[15];
  const float* w3    = (const float*)d_in[16];
  const float* b3    = (const float*)d_in[17];
  const float* fing  = (const float*)d_in[18];
  const float* finb  = (const float*)d_in[19];

  char* ws = (char*)d_ws;
  // Workspace layout (125.0 MB total), bytes:
  //  R0 x_res fp32            [0,          33554432)
  //  R1 hn bf16 multiplex     [33554432,   50331648)   ln1-out -> attnb -> ln2-out -> g
  //  R2 big bf16              [50331648,  117440512)   qkv -> (u | gl) -> mean partials
  //  R3 wT bf16               [117440512, 130809856)
  //  R4 stats float2          [130809856, 131072000)
  float* x_res = (float*)(ws);
  unsigned short* hn   = (unsigned short*)(ws + 33554432);
  unsigned short* big  = (unsigned short*)(ws + 50331648);
  unsigned short* glc  = (unsigned short*)(ws + 83886080);
  unsigned short* wT   = (unsigned short*)(ws + 117440512);
  float2* stats = (float2*)(ws + 130809856);
  float* part  = (float*)big;  // mean partials: big is dead by then

  unsigned short* qkvwT = wT;                 // 6*768*256
  unsigned short* outwT = wT + 1179648;       // 6*256*256
  unsigned short* w1T   = wT + 1572864;       // 6*1024*256
  unsigned short* w2T   = wT + 3145728;       // 6*512*1024
  unsigned short* w3T   = wT + 6291456;       // 6*256*256

  wtrans_kernel<<<dim3(12, 4, 6), 256, 0, stream>>>(qkvw, qkvwT, 256, 768);
  wtrans_kernel<<<dim3(4, 4, 6), 256, 0, stream>>>(outw, outwT, 256, 256);
  wtrans_kernel<<<dim3(16, 4, 6), 256, 0, stream>>>(w1, w1T, 256, 1024);
  wtrans_kernel<<<dim3(8, 16, 6), 256, 0, stream>>>(w2, w2T, 1024, 512);
  wtrans_kernel<<<dim3(4, 4, 6), 256, 0, stream>>>(w3, w3T, 256, 256);
  embed_kernel<<<8192, 256, 0, stream>>>((const float4*)x, (const float4*)cemb,
                                         (const float4*)pemb, (float4*)x_res);
  for (int l = 0; l < 6; ++l) {
    ln_kernel<0><<<8192, 256, 0, stream>>>(x_res, ln1g + l * 256, ln1b + l * 256, hn, nullptr);
    gemm_kernel<0><<<dim3(6, 256), 256, 0, stream>>>(hn, qkvwT + (size_t)l * 196608,
                                                     qkvb + l * 768, nullptr, nullptr, big,
                                                     768, 256);
    attn_kernel<<<1024, 256, 0, stream>>>(big, cbias, hn);  // attnb -> R1 (ln1-out dead)
    gemm_kernel<2><<<dim3(2, 256), 256, 0, stream>>>(hn, outwT + (size_t)l * 65536,
                                                     outbv + l * 256, cbias, x_res, nullptr,
                                                     256, 256);
    ln_kernel<0><<<8192, 256, 0, stream>>>(x_res, ln2g + l * 256, ln2b + l * 256, hn, nullptr);
    // MLP in 2 row-chunks of 16384 (fits in R2 after qkv is consumed)
    for (int c = 0; c < 2; ++c) {
      const size_t ro = (size_t)c * 16384 * 256;
      gemm_kernel<1><<<dim3(8, 128), 256, 0, stream>>>(hn + ro, w1T + (size_t)l * 262144,
                                                       b1 + l * 1024, nullptr, nullptr, big,
                                                       1024, 256);
      gemm_kernel<0><<<dim3(4, 128), 256, 0, stream>>>(big, w2T + (size_t)l * 524288,
                                                       b2 + l * 512, nullptr, nullptr, glc,
                                                       512, 1024);
      swiglu_kernel<<<4096, 256, 0, stream>>>(glc, hn + ro);
      gemm_kernel<3><<<dim3(2, 128), 256, 0, stream>>>(hn + ro, w3T + (size_t)l * 65536,
                                                       b3 + l * 256, nullptr, x_res + ro,
                                                       nullptr, 256, 256);
    }
  }
  ln_kernel<1><<<8192, 256, 0, stream>>>(x_res, nullptr, nullptr, nullptr, stats);
  mean_part_kernel<<<dim3(128, 2), 256, 0, stream>>>(x_res, stats, part);
  mean_fin_kernel<<<128, 256, 0, stream>>>(part, fing, finb, (float*)d_out);
}

// Round 6
// 1740.124 us; speedup vs baseline: 1.2661x; 1.0480x over previous
//
#include <hip/hip_runtime.h>

// ---------- types / helpers ----------
typedef __bf16 bx8 __attribute__((ext_vector_type(8)));
typedef float fx4 __attribute__((ext_vector_type(4)));

#define GAS(p) ((const __attribute__((address_space(1))) void*)(const void*)(p))
#define LAS(p) ((__attribute__((address_space(3))) void*)(void*)(p))

__device__ __forceinline__ unsigned short f2bf(float f) {
  return __builtin_bit_cast(unsigned short, (__bf16)f);  // native RTNE
}
__device__ __forceinline__ float bf2f(unsigned short s) {
  unsigned u = ((unsigned)s) << 16;
  return __builtin_bit_cast(float, u);
}

// ---------- tiled weight transpose + bf16 cast: dst[l][n][k] = (bf16)src[l][k][n] ----------
__global__ __launch_bounds__(256) void wtrans_kernel(const float* __restrict__ src,
                                                     unsigned short* __restrict__ dst,
                                                     int K, int N) {
  __shared__ unsigned short t[64][68];
  const int l = blockIdx.z;
  const float* s = src + (size_t)l * K * N;
  unsigned short* d = dst + (size_t)l * N * K;
  const int n0 = blockIdx.x * 64, k0 = blockIdx.y * 64;
  const int tx = threadIdx.x & 63, ty = threadIdx.x >> 6;
#pragma unroll
  for (int r = 0; r < 64; r += 4)
    t[tx][ty + r] = f2bf(s[(size_t)(k0 + ty + r) * N + n0 + tx]);
  __syncthreads();
#pragma unroll
  for (int r = 0; r < 64; r += 4)
    d[(size_t)(n0 + ty + r) * K + k0 + tx] = t[ty + r][tx];
}

// ---------- embed: x + col_emb[t] + pos_emb[t+1] ----------
__global__ __launch_bounds__(256) void embed_kernel(const float4* __restrict__ x,
                                                    const float4* __restrict__ ce,
                                                    const float4* __restrict__ pe,
                                                    float4* __restrict__ o) {
  int i = blockIdx.x * 256 + threadIdx.x;
  int c4 = i & 63;
  int t = (i >> 6) & 255;
  float4 a = x[i], b = ce[t * 64 + c4], p = pe[(t + 1) * 64 + c4];
  o[i] = make_float4(a.x + b.x + p.x, a.y + b.y + p.y, a.z + b.z + p.z, a.w + b.w + p.w);
}

// ---------- LayerNorm ----------
template <int MODE>
__global__ __launch_bounds__(256) void ln_kernel(const float* __restrict__ x,
                                                 const float* __restrict__ gw,
                                                 const float* __restrict__ bw,
                                                 unsigned short* __restrict__ out,
                                                 float2* __restrict__ stats) {
  int row = blockIdx.x * 4 + (threadIdx.x >> 6);
  int lane = threadIdx.x & 63;
  const float4 v = *(const float4*)(x + (size_t)row * 256 + lane * 4);
  float s = v.x + v.y + v.z + v.w;
  float q = v.x * v.x + v.y * v.y + v.z * v.z + v.w * v.w;
#pragma unroll
  for (int off = 1; off < 64; off <<= 1) {
    s += __shfl_xor(s, off);
    q += __shfl_xor(q, off);
  }
  float mean = s * (1.0f / 256.0f);
  float rs = rsqrtf(q * (1.0f / 256.0f) - mean * mean + 1e-5f);
  if (MODE == 1) {
    if (lane == 0) stats[row] = make_float2(mean, rs);
    return;
  }
  float4 gv = *(const float4*)(gw + lane * 4);
  float4 bv = *(const float4*)(bw + lane * 4);
  ushort4 o;
  o.x = f2bf((v.x - mean) * rs * gv.x + bv.x);
  o.y = f2bf((v.y - mean) * rs * gv.y + bv.y);
  o.z = f2bf((v.z - mean) * rs * gv.z + bv.z);
  o.w = f2bf((v.w - mean) * rs * gv.w + bv.w);
  *(ushort4*)(out + (size_t)row * 256 + lane * 4) = o;
}

// ---------- swiglu ----------
__global__ __launch_bounds__(256) void swiglu_kernel(const unsigned short* __restrict__ gl,
                                                     unsigned short* __restrict__ g) {
  int i = blockIdx.x * 256 + threadIdx.x;
  int m = i >> 6;
  int c4 = (i & 63) * 4;
  const ushort4 a = *(const ushort4*)(gl + (size_t)m * 512 + c4);
  const ushort4 gt = *(const ushort4*)(gl + (size_t)m * 512 + 256 + c4);
  ushort4 o;
  o.x = f2bf(bf2f(a.x) / (1.0f + __expf(-bf2f(gt.x))));
  o.y = f2bf(bf2f(a.y) / (1.0f + __expf(-bf2f(gt.y))));
  o.z = f2bf(bf2f(a.z) / (1.0f + __expf(-bf2f(gt.z))));
  o.w = f2bf(bf2f(a.w) / (1.0f + __expf(-bf2f(gt.w))));
  *(ushort4*)(g + (size_t)m * 256 + c4) = o;
}

// ---------- final mean, two-stage ----------
__global__ __launch_bounds__(256) void mean_part_kernel(const float* __restrict__ x,
                                                        const float2* __restrict__ stats,
                                                        float* __restrict__ part) {
  int b = blockIdx.x, half = blockIdx.y, c = threadIdx.x;
  const float* xb = x + (size_t)b * 65536 + half * 32768;
  const float2* st = stats + b * 256 + half * 128;
  float acc = 0.f;
#pragma unroll 4
  for (int t = 0; t < 128; ++t) {
    float2 s = st[t];
    acc += (xb[t * 256 + c] - s.x) * s.y;
  }
  part[(size_t)(b * 2 + half) * 256 + c] = acc;
}
__global__ __launch_bounds__(256) void mean_fin_kernel(const float* __restrict__ part,
                                                       const float* __restrict__ fg,
                                                       const float* __restrict__ fb,
                                                       float* __restrict__ out) {
  int b = blockIdx.x, c = threadIdx.x;
  out[b * 256 + c] =
      (part[(size_t)(2 * b) * 256 + c] + part[(size_t)(2 * b + 1) * 256 + c]) *
          (1.0f / 256.0f) * fg[c] + fb[c];
}

// ---------- GEMM with OPERAND-SWAPPED MFMA (vectorized epilogue) ----------
// acc[i][j] = mfma(bq[j], af[i], ·): value at lane (g,lr) reg r is
//   C[m = m0+wr*64+i*16+lr][n = n0+wc*64+j*16+4g+r]  (4 consecutive cols/lane)
// EP 0: out_bf16 = acc + bvec                 (ushort4 stores)
// EP 1: out_bf16 = gelu_exact(acc + bvec)
// EP 2: resid += acc + bvec + col_bias[s][n]  (float4 RMW)
// EP 3: resid += acc + bvec                   (float4 RMW)
// EP 4: qkv: cols<512 -> outb (ushort4); cols>=512 (V part) -> vT in the
//       attn-Vl swizzled image: vT[(b*8+h)*8192 + up*8 + j],
//       u = (s>>5)*128 + ((s>>2)&3)*32 + d, up = XOR-swizzle(u),
//       j = (s&3)+4*((s>>4)&1), s = m&255, d = (n-512)&31.
template <int EP>
__global__ __launch_bounds__(256) void gemm_kernel(const unsigned short* __restrict__ A,
                                                   const unsigned short* __restrict__ BT,
                                                   const float* __restrict__ bvec,
                                                   const float* __restrict__ cbias,
                                                   float* __restrict__ resid,
                                                   unsigned short* __restrict__ outb,
                                                   int N, int K) {
  __shared__ unsigned short lA[2][128 * 32];
  __shared__ unsigned short lB[2][128 * 32];
  const int tid = threadIdx.x;
  const int lane = tid & 63, w = tid >> 6;
  const int wr = w >> 1, wc = w & 1;
  const int g = lane >> 4, lr = lane & 15;
  const int m0 = blockIdx.y * 128, n0 = blockIdx.x * 128;
  fx4 acc[4][4] = {};

  auto STAGE = [&](int buf, int kk) {
#pragma unroll
    for (int r = 0; r < 2; ++r) {
      int u = r * 256 + tid;
      int row = u >> 2, sl = u & 3;
      int c = sl ^ ((row >> 1) & 3);
      __builtin_amdgcn_global_load_lds(GAS(A + (size_t)(m0 + row) * K + kk + c * 8),
                                       LAS(&lA[buf][u * 8]), 16, 0, 0);
      __builtin_amdgcn_global_load_lds(GAS(BT + (size_t)(n0 + row) * K + kk + c * 8),
                                       LAS(&lB[buf][u * 8]), 16, 0, 0);
    }
  };
  auto COMPUTE = [&](int buf) {
    bx8 af[4], bq[4];
#pragma unroll
    for (int i = 0; i < 4; ++i) {
      int row = wr * 64 + i * 16 + lr;
      af[i] = *(const bx8*)&lA[buf][row * 32 + (g ^ ((row >> 1) & 3)) * 8];
      int col = wc * 64 + i * 16 + lr;
      bq[i] = *(const bx8*)&lB[buf][col * 32 + (g ^ ((col >> 1) & 3)) * 8];
    }
#pragma unroll
    for (int i = 0; i < 4; ++i)
#pragma unroll
      for (int j = 0; j < 4; ++j)
        acc[i][j] = __builtin_amdgcn_mfma_f32_16x16x32_bf16(bq[j], af[i], acc[i][j], 0, 0, 0);
  };

  STAGE(0, 0);
  asm volatile("s_waitcnt vmcnt(0)" ::: "memory");
  __syncthreads();
  int cur = 0;
  const int nt = K >> 5;
  for (int t2 = 1; t2 < nt; ++t2) {
    STAGE(cur ^ 1, t2 * 32);
    COMPUTE(cur);
    __syncthreads();
    cur ^= 1;
  }
  COMPUTE(cur);

#pragma unroll
  for (int i = 0; i < 4; ++i) {
    const int m = m0 + wr * 64 + i * 16 + lr;
#pragma unroll
    for (int j = 0; j < 4; ++j) {
      const int nc = n0 + wc * 64 + j * 16 + g * 4;
      const float4 bv = *(const float4*)(bvec + nc);
      float v0 = acc[i][j][0] + bv.x, v1 = acc[i][j][1] + bv.y;
      float v2 = acc[i][j][2] + bv.z, v3 = acc[i][j][3] + bv.w;
      if constexpr (EP == 1) {
        v0 = 0.5f * v0 * (1.0f + erff(v0 * 0.70710678118654752f));
        v1 = 0.5f * v1 * (1.0f + erff(v1 * 0.70710678118654752f));
        v2 = 0.5f * v2 * (1.0f + erff(v2 * 0.70710678118654752f));
        v3 = 0.5f * v3 * (1.0f + erff(v3 * 0.70710678118654752f));
      }
      if constexpr (EP == 0 || EP == 1) {
        ushort4 st;
        st.x = f2bf(v0); st.y = f2bf(v1); st.z = f2bf(v2); st.w = f2bf(v3);
        *(ushort4*)(outb + (size_t)m * N + nc) = st;
      } else if constexpr (EP == 2 || EP == 3) {
        if constexpr (EP == 2) {
          const float4 cb = *(const float4*)(cbias + (size_t)(m & 255) * 256 + nc);
          v0 += cb.x; v1 += cb.y; v2 += cb.z; v3 += cb.w;
        }
        float4* rp = (float4*)(resid + (size_t)m * N + nc);
        float4 old = *rp;
        *rp = make_float4(old.x + v0, old.y + v1, old.z + v2, old.w + v3);
      } else {  // EP 4
        if (nc < 512) {
          ushort4 st;
          st.x = f2bf(v0); st.y = f2bf(v1); st.z = f2bf(v2); st.w = f2bf(v3);
          *(ushort4*)(outb + (size_t)m * N + nc) = st;
        } else {
          unsigned short* vTp = (unsigned short*)resid;
          const int s = m & 255, b = m >> 8;
          const int hv = nc - 512;
          const int h = hv >> 5, d0 = hv & 31;
          const int jj = (s & 3) + 4 * ((s >> 4) & 1);
          const int ub = (s >> 5) * 128 + ((s >> 2) & 3) * 32 + d0;
          unsigned short* base = vTp + (size_t)(b * 8 + h) * 8192;
          const float vv[4] = {v0, v1, v2, v3};
#pragma unroll
          for (int r = 0; r < 4; ++r) {
            int u = ub + r;
            int up = (u & ~7) | ((u & 7) ^ ((u >> 3) & 7));
            base[up * 8 + jj] = f2bf(vv[r]);
          }
        }
      }
    }
  }
}

// ---------- fused attention v3: V staged from pre-transposed vT ----------
// NOTE: NO min-waves launch-bounds arg — (256,4) capped VGPR at 64 and spilled
// p[16][4] to scratch. Plain (256).
__global__ __launch_bounds__(256) void attn_kernel(const unsigned short* __restrict__ qkv,
                                                   const unsigned short* __restrict__ vT,
                                                   const float* __restrict__ cbias,
                                                   unsigned short* __restrict__ attnb) {
  __shared__ unsigned short Kl[256 * 32];  // [s][d], 16B-unit swizzled
  __shared__ unsigned short Vl[1024 * 8];  // swizzled image, copied linearly from vT
  const int bh = blockIdx.x, b = bh >> 3, h = bh & 7;
  const int tid = threadIdx.x, lane = tid & 63, w = tid >> 6;
  const int g = lane >> 4, lr = lane & 15;
  const unsigned short* qb_ = qkv + (size_t)b * 196608;
  const unsigned short* vTb = vT + (size_t)bh * 8192;
#pragma unroll
  for (int r = 0; r < 4; ++r) {
    int u = r * 256 + tid;
    int s = u >> 2, sl = u & 3;
    int c = sl ^ ((s >> 1) & 3);
    __builtin_amdgcn_global_load_lds(GAS(qb_ + (size_t)s * 768 + 256 + h * 32 + c * 8),
                                     LAS(&Kl[u * 8]), 16, 0, 0);
    __builtin_amdgcn_global_load_lds(GAS(vTb + u * 8), LAS(&Vl[u * 8]), 16, 0, 0);
  }
  asm volatile("s_waitcnt vmcnt(0)" ::: "memory");
  __syncthreads();
  const float scale = 0.17677669529663689f;
  const fx4 zero = {0.f, 0.f, 0.f, 0.f};
#pragma unroll 1
  for (int it = 0; it < 4; ++it) {
    const int t = it * 64 + w * 16 + lr;
    bx8 qf = *(const bx8*)(qb_ + (size_t)t * 768 + h * 32 + g * 8);
    float p[16][4];
    float mx = -1e30f;
#pragma unroll
    for (int n = 0; n < 16; ++n) {
      int sr = n * 16 + lr;
      bx8 kf = *(const bx8*)&Kl[sr * 32 + (g ^ ((sr >> 1) & 3)) * 8];
      fx4 sc = __builtin_amdgcn_mfma_f32_16x16x32_bf16(kf, qf, zero, 0, 0, 0);
      const float4 cb = *(const float4*)(cbias + (size_t)t * 256 + n * 16 + g * 4);
      p[n][0] = sc[0] * scale + cb.x;
      p[n][1] = sc[1] * scale + cb.y;
      p[n][2] = sc[2] * scale + cb.z;
      p[n][3] = sc[3] * scale + cb.w;
      mx = fmaxf(mx, fmaxf(fmaxf(p[n][0], p[n][1]), fmaxf(p[n][2], p[n][3])));
    }
    mx = fmaxf(mx, __shfl_xor(mx, 16));
    mx = fmaxf(mx, __shfl_xor(mx, 32));
    float sum = 0.f;
    bx8 bq[8];
#pragma unroll
    for (int c = 0; c < 8; ++c) {
      union { bx8 v; unsigned short u[8]; } pk;
#pragma unroll
      for (int jj = 0; jj < 8; ++jj) {
        float e = __expf(p[2 * c + (jj >> 2)][jj & 3] - mx);
        sum += e;
        pk.u[jj] = f2bf(e);
      }
      bq[c] = pk.v;
    }
    sum += __shfl_xor(sum, 16);
    sum += __shfl_xor(sum, 32);
    const float inv = 1.0f / sum;
    fx4 oa0 = zero, oa1 = zero;
#pragma unroll
    for (int c = 0; c < 8; ++c) {
      int u0 = c * 128 + g * 32 + lr;
      int u0p = (u0 & ~7) | ((u0 & 7) ^ ((u0 >> 3) & 7));
      bx8 vf0 = *(const bx8*)&Vl[u0p * 8];
      oa0 = __builtin_amdgcn_mfma_f32_16x16x32_bf16(vf0, bq[c], oa0, 0, 0, 0);
      int u1 = u0 + 16;
      int u1p = (u1 & ~7) | ((u1 & 7) ^ ((u1 >> 3) & 7));
      bx8 vf1 = *(const bx8*)&Vl[u1p * 8];
      oa1 = __builtin_amdgcn_mfma_f32_16x16x32_bf16(vf1, bq[c], oa1, 0, 0, 0);
    }
    ushort4 o0, o1;
    o0.x = f2bf(oa0[0] * inv); o0.y = f2bf(oa0[1] * inv);
    o0.z = f2bf(oa0[2] * inv); o0.w = f2bf(oa0[3] * inv);
    o1.x = f2bf(oa1[0] * inv); o1.y = f2bf(oa1[1] * inv);
    o1.z = f2bf(oa1[2] * inv); o1.w = f2bf(oa1[3] * inv);
    unsigned short* orow = attnb + (size_t)(b * 256 + t) * 256 + h * 32;
    *(ushort4*)(orow + 4 * g) = o0;
    *(ushort4*)(orow + 16 + 4 * g) = o1;
  }
}

// ---------- orchestration ----------
extern "C" void kernel_launch(void* const* d_in, const int* in_sizes, int n_in,
                              void* d_out, int out_size, void* d_ws, size_t ws_size,
                              hipStream_t stream) {
  (void)in_sizes; (void)n_in; (void)out_size; (void)ws_size;
  const float* x     = (const float*)d_in[0];
  const float* cemb  = (const float*)d_in[1];
  const float* pemb  = (const float*)d_in[2];
  const float* cbias = (const float*)d_in[3];
  const float* ln1g  = (const float*)d_in[4];
  const float* ln1b  = (const float*)d_in[5];
  const float* qkvw  = (const float*)d_in[6];
  const float* qkvb  = (const float*)d_in[7];
  const float* outw  = (const float*)d_in[8];
  const float* outbv = (const float*)d_in[9];
  const float* ln2g  = (const float*)d_in[10];
  const float* ln2b  = (const float*)d_in[11];
  const float* w1    = (const float*)d_in[12];
  const float* b1    = (const float*)d_in[13];
  const float* w2    = (const float*)d_in[14];
  const float* b2    = (const float*)d_in[15];
  const float* w3    = (const float*)d_in[16];
  const float* b3    = (const float*)d_in[17];
  const float* fing  = (const float*)d_in[18];
  const float* finb  = (const float*)d_in[19];

  char* ws = (char*)d_ws;
  // Workspace layout (125.0 MB total), bytes:
  //  R0 x_res fp32            [0,          33554432)
  //  R1 hn bf16 multiplex     [33554432,   50331648)   ln1-out -> attnb -> ln2-out -> g
  //  R2 big bf16              [50331648,  117440512)
  //     qkv [50331648, 100663296) + vT [100663296, 117440512)   (attn phase)
  //     u   [50331648, 83886080)  + gl [83886080, 100663296)    (MLP phase)
  //  R3 wT bf16               [117440512, 130809856)
  //  R4 stats float2          [130809856, 131072000)
  float* x_res = (float*)(ws);
  unsigned short* hn   = (unsigned short*)(ws + 33554432);
  unsigned short* big  = (unsigned short*)(ws + 50331648);
  unsigned short* glc  = (unsigned short*)(ws + 83886080);
  unsigned short* vT   = (unsigned short*)(ws + 100663296);
  unsigned short* wT   = (unsigned short*)(ws + 117440512);
  float2* stats = (float2*)(ws + 130809856);
  float* part  = (float*)big;  // mean partials: big dead by then

  unsigned short* qkvwT = wT;                 // 6*768*256
  unsigned short* outwT = wT + 1179648;       // 6*256*256
  unsigned short* w1T   = wT + 1572864;       // 6*1024*256
  unsigned short* w2T   = wT + 3145728;       // 6*512*1024
  unsigned short* w3T   = wT + 6291456;       // 6*256*256

  wtrans_kernel<<<dim3(12, 4, 6), 256, 0, stream>>>(qkvw, qkvwT, 256, 768);
  wtrans_kernel<<<dim3(4, 4, 6), 256, 0, stream>>>(outw, outwT, 256, 256);
  wtrans_kernel<<<dim3(16, 4, 6), 256, 0, stream>>>(w1, w1T, 256, 1024);
  wtrans_kernel<<<dim3(8, 16, 6), 256, 0, stream>>>(w2, w2T, 1024, 512);
  wtrans_kernel<<<dim3(4, 4, 6), 256, 0, stream>>>(w3, w3T, 256, 256);
  embed_kernel<<<8192, 256, 0, stream>>>((const float4*)x, (const float4*)cemb,
                                         (const float4*)pemb, (float4*)x_res);
  for (int l = 0; l < 6; ++l) {
    ln_kernel<0><<<8192, 256, 0, stream>>>(x_res, ln1g + l * 256, ln1b + l * 256, hn, nullptr);
    gemm_kernel<4><<<dim3(6, 256), 256, 0, stream>>>(hn, qkvwT + (size_t)l * 196608,
                                                     qkvb + l * 768, nullptr, (float*)vT,
                                                     big, 768, 256);
    attn_kernel<<<1024, 256, 0, stream>>>(big, vT, cbias, hn);
    gemm_kernel<2><<<dim3(2, 256), 256, 0, stream>>>(hn, outwT + (size_t)l * 65536,
                                                     outbv + l * 256, cbias, x_res, nullptr,
                                                     256, 256);
    ln_kernel<0><<<8192, 256, 0, stream>>>(x_res, ln2g + l * 256, ln2b + l * 256, hn, nullptr);
    for (int c = 0; c < 2; ++c) {
      const size_t ro = (size_t)c * 16384 * 256;
      gemm_kernel<1><<<dim3(8, 128), 256, 0, stream>>>(hn + ro, w1T + (size_t)l * 262144,
                                                       b1 + l * 1024, nullptr, nullptr, big,
                                                       1024, 256);
      gemm_kernel<0><<<dim3(4, 128), 256, 0, stream>>>(big, w2T + (size_t)l * 524288,
                                                       b2 + l * 512, nullptr, nullptr, glc,
                                                       512, 1024);
      swiglu_kernel<<<4096, 256, 0, stream>>>(glc, hn + ro);
      gemm_kernel<3><<<dim3(2, 128), 256, 0, stream>>>(hn + ro, w3T + (size_t)l * 65536,
                                                       b3 + l * 256, nullptr, x_res + ro,
                                                       nullptr, 256, 256);
    }
  }
  ln_kernel<1><<<8192, 256, 0, stream>>>(x_res, nullptr, nullptr, nullptr, stats);
  mean_part_kernel<<<dim3(128, 2), 256, 0, stream>>>(x_res, stats, part);
  mean_fin_kernel<<<128, 256, 0, stream>>>(part, fing, finb, (float*)d_out);
}